// Round 7
// baseline (231.039 us; speedup 1.0000x reference)
//
#include <hip/hip_runtime.h>
#include <math.h>

#define HIDDEN 64
#define TOTAL  4417   // 5*64 + 1 + 64*64
#define TSTEPS 64

// coefficient layout per batch row:
//   w_ih  [0,   64)
//   w_hh  [64,  4160)   row-major [k][j]: 64 + k*64 + j
//   b_ih  [4160,4224)
//   b_hh  [4224,4288)
//   fc_w  [4288,4352)
//   fc_b  [4352,4353)
//   h0    [4353,4417)

typedef float f4 __attribute__((ext_vector_type(4)));

// R1-R6 post-mortem: total VALU-issue time was invariant (~141us) across all
// register-allocation variants, and every round landed in the 173-226us band
// => the bottleneck is the LDS pipe: 16 ds_read_b128 h-broadcasts per step
// (16.8M total, ~8cyc each on the per-CU LDS pipe ~= 200us). Fix: 1 read per
// step (each lane takes 4 h values) + DPP row_newbcast to distribute within
// 16-lane rows. DS instrs/step: 17 -> 2.

// broadcast lane (16*row + i) to all lanes of its row; ctrl 0x150+i = ROW_NEWBCAST
#define BC(v, i) __int_as_float(__builtin_amdgcn_update_dpp( \
    0, __float_as_int(v), 0x150 + (i), 0xF, 0xF, true))

__global__
__attribute__((amdgpu_flat_work_group_size(64, 64), amdgpu_waves_per_eu(4)))
void rnn_fused_kernel(const float* __restrict__ coeff,
                      const float* __restrict__ xin,
                      float* __restrict__ out)
{
    const int b    = blockIdx.x;
    const int lane = threadIdx.x;              // 0..63, one wave per block

    const float* __restrict__ c = coeff + (size_t)b * TOTAL;

    __shared__ __align__(16) float hsh[HIDDEN];   // h vector (single-wave block)

    // ---- per-lane parameters ----
    const float wih  = c[lane];
    const float bias = c[4160 + lane] + c[4224 + lane];
    const float fcw  = c[4288 + lane];
    const float fcb  = c[4352];
    const float h0   = c[4353 + lane];
    const float xv   = xin[(size_t)b * TSTEPS + lane];  // lane t holds x[b][t]

    // ---- W row: lane k owns w_hh[b][k][*] in 64 NAMED registers ----
    // asm-volatile loads: non-rematerializable, non-sinkable, arch-VGPR defs.
    // Scalar dword loads: row base only 4-byte aligned (TOTAL*4 % 16 != 0).
    const float* wrow = c + HIDDEN + (size_t)lane * HIDDEN;

#define WLOAD(n, offs) float w##n; \
    asm volatile("global_load_dword %0, %1, off offset:" offs \
                 : "=v"(w##n) : "v"(wrow));
    WLOAD(0,"0")     WLOAD(1,"4")     WLOAD(2,"8")     WLOAD(3,"12")
    WLOAD(4,"16")    WLOAD(5,"20")    WLOAD(6,"24")    WLOAD(7,"28")
    WLOAD(8,"32")    WLOAD(9,"36")    WLOAD(10,"40")   WLOAD(11,"44")
    WLOAD(12,"48")   WLOAD(13,"52")   WLOAD(14,"56")   WLOAD(15,"60")
    WLOAD(16,"64")   WLOAD(17,"68")   WLOAD(18,"72")   WLOAD(19,"76")
    WLOAD(20,"80")   WLOAD(21,"84")   WLOAD(22,"88")   WLOAD(23,"92")
    WLOAD(24,"96")   WLOAD(25,"100")  WLOAD(26,"104")  WLOAD(27,"108")
    WLOAD(28,"112")  WLOAD(29,"116")  WLOAD(30,"120")  WLOAD(31,"124")
    WLOAD(32,"128")  WLOAD(33,"132")  WLOAD(34,"136")  WLOAD(35,"140")
    WLOAD(36,"144")  WLOAD(37,"148")  WLOAD(38,"152")  WLOAD(39,"156")
    WLOAD(40,"160")  WLOAD(41,"164")  WLOAD(42,"168")  WLOAD(43,"172")
    WLOAD(44,"176")  WLOAD(45,"180")  WLOAD(46,"184")  WLOAD(47,"188")
    WLOAD(48,"192")  WLOAD(49,"196")  WLOAD(50,"200")  WLOAD(51,"204")
    WLOAD(52,"208")  WLOAD(53,"212")  WLOAD(54,"216")  WLOAD(55,"220")
    WLOAD(56,"224")  WLOAD(57,"228")  WLOAD(58,"232")  WLOAD(59,"236")
    WLOAD(60,"240")  WLOAD(61,"244")  WLOAD(62,"248")  WLOAD(63,"252")
#undef WLOAD
    asm volatile("s_waitcnt vmcnt(0)" ::: "memory");
    __builtin_amdgcn_sched_barrier(0);   // rule #18: nothing hoists past the wait

    hsh[lane] = h0;
    __builtin_amdgcn_wave_barrier();

    float hn = h0;

    #pragma unroll 1
    for (int t = 0; t < TSTEPS; ++t) {
        // ONE LDS read per step: lane k takes h[4*(k&15) .. +3]; each
        // 16-lane row holds the whole h vector (rows replicate -> broadcast).
        const f4 hq = *reinterpret_cast<const f4*>(&hsh[4 * (lane & 15)]);
        __builtin_amdgcn_wave_barrier();   // read precedes this step's write

        const float xt = __int_as_float(
            __builtin_amdgcn_readlane(__float_as_int(xv), t));
        float a0 = fmaf(xt, wih, bias);
        float a1 = 0.0f, a2 = 0.0f, a3 = 0.0f;

        // acc_k += sum_j h[j]*W[k][j]: h[4i+e] = row_newbcast:i of hq[e].
        // 64 mov_dpp+fmac pairs; GCNDPPCombine fuses into v_fmac_f32_dpp.
#define ACC4(i, wa, wb, wc, wd) \
        a0 = fmaf(BC(hq.x, i), wa, a0); \
        a1 = fmaf(BC(hq.y, i), wb, a1); \
        a2 = fmaf(BC(hq.z, i), wc, a2); \
        a3 = fmaf(BC(hq.w, i), wd, a3);
        ACC4(0,  w0,  w1,  w2,  w3)
        ACC4(1,  w4,  w5,  w6,  w7)
        ACC4(2,  w8,  w9,  w10, w11)
        ACC4(3,  w12, w13, w14, w15)
        ACC4(4,  w16, w17, w18, w19)
        ACC4(5,  w20, w21, w22, w23)
        ACC4(6,  w24, w25, w26, w27)
        ACC4(7,  w28, w29, w30, w31)
        ACC4(8,  w32, w33, w34, w35)
        ACC4(9,  w36, w37, w38, w39)
        ACC4(10, w40, w41, w42, w43)
        ACC4(11, w44, w45, w46, w47)
        ACC4(12, w48, w49, w50, w51)
        ACC4(13, w52, w53, w54, w55)
        ACC4(14, w56, w57, w58, w59)
        ACC4(15, w60, w61, w62, w63)
#undef ACC4
        const float acc = (a0 + a1) + (a2 + a3);

        // tanh(a) = 1 - 2/(e^{2a}+1); robust at +-inf
        const float e = __expf(acc + acc);
        hn = 1.0f - 2.0f * __builtin_amdgcn_rcpf(e + 1.0f);

        hsh[lane] = hn;                    // ONE LDS write per step
        __builtin_amdgcn_wave_barrier();   // write precedes next-iter read
    }

    // ---- readout: pred = sum_k h[k]*fc_w[k] + fc_b ----
    float p = hn * fcw;
    #pragma unroll
    for (int off = 32; off > 0; off >>= 1)
        p += __shfl_xor(p, off, 64);

    if (lane == 0) out[b] = p + fcb;
}

extern "C" void kernel_launch(void* const* d_in, const int* in_sizes, int n_in,
                              void* d_out, int out_size, void* d_ws, size_t ws_size,
                              hipStream_t stream)
{
    const float* coeff = (const float*)d_in[0];
    const float* xin   = (const float*)d_in[1];
    float* out         = (float*)d_out;

    const int B = in_sizes[0] / TOTAL;   // 16384

    rnn_fused_kernel<<<B, HIDDEN, 0, stream>>>(coeff, xin, out);
}

// Round 9
// 165.515 us; speedup vs baseline: 1.3959x; 1.3959x over previous
//
#include <hip/hip_runtime.h>
#include <math.h>

#define HIDDEN 64
#define TOTAL  4417   // 5*64 + 1 + 64*64
#define TSTEPS 64

// coefficient layout per batch row:
//   w_ih  [0,   64)
//   w_hh  [64,  4160)   row-major [k][j]: 64 + k*64 + j
//   b_ih  [4160,4224)
//   b_hh  [4224,4288)
//   fc_w  [4288,4352)
//   fc_b  [4352,4353)
//   h0    [4353,4417)
//
// R8 post-mortem: NaN from the v_readlane->v_fma SGPR hazard (no compiler
// to insert wait states inside asm). Also 16 broadcast ds_read_b128/step
// saturates the per-CU LDS pipe (~140us) even when correct.
// R9: explicit-physreg asm loop, h distributed by FUSED v_fmac_f32_dpp
// row_newbcast (what R7 wanted but the compiler wouldn't fuse). Per step:
// 1 ds_read_b128 + 1 ds_read_b32 (x_t) + 1 ds_write_b32. All-VGPR dataflow.
//   v24..v87  W row (64)     v120..v123 accumulators   v126 x_t
//   v88..v91  h quad         v124 hn, v125 tmp         v127 x cursor
// LDS layout: lds[0..63] = h, lds[64..127] = x row.
// h quad: lane k reads h[4*(k&15) .. +3]; every 16-lane row holds all of h,
// so row_newbcast:i delivers h[4i+e] from row-lane i to the whole row.

#define WL(r, o)   "global_load_dword v" #r ", %[wr], off offset:" #o "\n\t"
#define DPP4(i, wa, wb, wc, wd) \
    "v_fmac_f32_dpp v120, v88, v" #wa " row_newbcast:" #i " row_mask:0xf bank_mask:0xf\n\t" \
    "v_fmac_f32_dpp v121, v89, v" #wb " row_newbcast:" #i " row_mask:0xf bank_mask:0xf\n\t" \
    "v_fmac_f32_dpp v122, v90, v" #wc " row_newbcast:" #i " row_mask:0xf bank_mask:0xf\n\t" \
    "v_fmac_f32_dpp v123, v91, v" #wd " row_newbcast:" #i " row_mask:0xf bank_mask:0xf\n\t"

__global__
__attribute__((amdgpu_flat_work_group_size(64, 64)))
void rnn_fused_kernel(const float* __restrict__ coeff,
                      const float* __restrict__ xin,
                      float* __restrict__ out)
{
    const int b    = blockIdx.x;
    const int lane = threadIdx.x;              // 0..63, one wave per block

    const float* __restrict__ c = coeff + (size_t)b * TOTAL;

    __shared__ __align__(16) float lds[128];   // [0,64): h   [64,128): x row

    // ---- per-lane parameters ----
    const float wih  = c[lane];
    const float bias = c[4160 + lane] + c[4224 + lane];
    const float fcw  = c[4288 + lane];
    const float fcb  = c[4352];
    const float h0   = c[4353 + lane];
    const float xv   = xin[(size_t)b * TSTEPS + lane];  // lane t holds x[b][t]

    const float* wrow = c + HIDDEN + (size_t)lane * HIDDEN;

    // DS addresses: low 32 bits of a generic LDS pointer = DS byte offset.
    const unsigned ha  = (unsigned)(unsigned long long)(const void*)lds;
    const unsigned hqa = ha + 16u * (unsigned)(lane & 15);  // h quad read addr
    const unsigned hw  = ha + 4u  * (unsigned)lane;         // h write addr

    lds[lane]      = h0;   // ds_writes ordered before the asm ("memory")
    lds[64 + lane] = xv;

    float hn;
    asm volatile(
        // ---- W row into v24..v87 (once) ----
        WL(24,0)  WL(25,4)  WL(26,8)  WL(27,12)  WL(28,16)  WL(29,20)  WL(30,24)  WL(31,28)
        WL(32,32) WL(33,36) WL(34,40) WL(35,44)  WL(36,48)  WL(37,52)  WL(38,56)  WL(39,60)
        WL(40,64) WL(41,68) WL(42,72) WL(43,76)  WL(44,80)  WL(45,84)  WL(46,88)  WL(47,92)
        WL(48,96) WL(49,100) WL(50,104) WL(51,108) WL(52,112) WL(53,116) WL(54,120) WL(55,124)
        WL(56,128) WL(57,132) WL(58,136) WL(59,140) WL(60,144) WL(61,148) WL(62,152) WL(63,156)
        WL(64,160) WL(65,164) WL(66,168) WL(67,172) WL(68,176) WL(69,180) WL(70,184) WL(71,188)
        WL(72,192) WL(73,196) WL(74,200) WL(75,204) WL(76,208) WL(77,212) WL(78,216) WL(79,220)
        WL(80,224) WL(81,228) WL(82,232) WL(83,236) WL(84,240) WL(85,244) WL(86,248) WL(87,252)
        "s_mov_b32 s20, 0\n\t"
        "v_add_u32 v127, 0x100, %[ha]\n\t"     // x cursor = &lds[64]
        "s_waitcnt vmcnt(0)\n\t"               // W resident
        "s_waitcnt lgkmcnt(0)\n"               // h0/x ds_writes complete
        "9:\n\t"
        "ds_read_b32 v126, v127\n\t"           // x_t (uniform addr broadcast)
        "ds_read_b128 v[88:91], %[hqa]\n\t"    // h[4*(lane&15) .. +3]
        "v_add_u32 v127, 4, v127\n\t"
        "s_waitcnt lgkmcnt(0)\n\t"
        "v_fma_f32 v120, v126, %[wih], %[bias]\n\t"
        "v_mov_b32 v121, 0\n\t"
        "v_mov_b32 v122, 0\n\t"
        "v_mov_b32 v123, 0\n\t"
        // 64 fused DPP fmacs: acc_e += h[4i+e] * W[k][4i+e]
        DPP4(0,  24, 25, 26, 27)
        DPP4(1,  28, 29, 30, 31)
        DPP4(2,  32, 33, 34, 35)
        DPP4(3,  36, 37, 38, 39)
        DPP4(4,  40, 41, 42, 43)
        DPP4(5,  44, 45, 46, 47)
        DPP4(6,  48, 49, 50, 51)
        DPP4(7,  52, 53, 54, 55)
        DPP4(8,  56, 57, 58, 59)
        DPP4(9,  60, 61, 62, 63)
        DPP4(10, 64, 65, 66, 67)
        DPP4(11, 68, 69, 70, 71)
        DPP4(12, 72, 73, 74, 75)
        DPP4(13, 76, 77, 78, 79)
        DPP4(14, 80, 81, 82, 83)
        DPP4(15, 84, 85, 86, 87)
        // combine + tanh(a) = 1 - 2/(exp2(2a*log2e)+1)
        "v_add_f32 v120, v120, v121\n\t"
        "v_add_f32 v122, v122, v123\n\t"
        "v_add_f32 v120, v120, v122\n\t"
        "v_mul_f32 v125, 0x4038aa3b, v120\n\t" // a * 2*log2(e)
        "v_exp_f32 v125, v125\n\t"
        "s_nop 1\n\t"                          // trans-use safety
        "v_add_f32 v125, 1.0, v125\n\t"
        "v_rcp_f32 v125, v125\n\t"
        "s_nop 1\n\t"
        "v_fma_f32 v124, -2.0, v125, 1.0\n\t"  // hn
        "ds_write_b32 %[hw], v124\n\t"         // in-order DS: next read sees it
        "s_add_u32 s20, s20, 1\n\t"
        "s_cmp_lt_u32 s20, 64\n\t"
        "s_cbranch_scc1 9b\n\t"
        "s_waitcnt lgkmcnt(0)\n\t"
        "v_mov_b32 %[hn], v124\n\t"
        : [hn] "=v"(hn)
        : [wr] "v"(wrow), [ha] "v"(ha), [hqa] "v"(hqa), [hw] "v"(hw),
          [wih] "v"(wih), [bias] "v"(bias)
        : "memory", "scc", "s20",
          "v24","v25","v26","v27","v28","v29","v30","v31",
          "v32","v33","v34","v35","v36","v37","v38","v39",
          "v40","v41","v42","v43","v44","v45","v46","v47",
          "v48","v49","v50","v51","v52","v53","v54","v55",
          "v56","v57","v58","v59","v60","v61","v62","v63",
          "v64","v65","v66","v67","v68","v69","v70","v71",
          "v72","v73","v74","v75","v76","v77","v78","v79",
          "v80","v81","v82","v83","v84","v85","v86","v87",
          "v88","v89","v90","v91","v92","v93","v94","v95",
          "v96","v97","v98","v99","v100","v101","v102","v103",
          "v104","v105","v106","v107","v108","v109","v110","v111",
          "v112","v113","v114","v115","v116","v117","v118","v119",
          "v120","v121","v122","v123","v124","v125","v126","v127");

    // ---- readout: pred = sum_k h[k]*fc_w[k] + fc_b ----
    float p = hn * fcw;
    #pragma unroll
    for (int off = 32; off > 0; off >>= 1)
        p += __shfl_xor(p, off, 64);

    if (lane == 0) out[b] = p + fcb;
}

extern "C" void kernel_launch(void* const* d_in, const int* in_sizes, int n_in,
                              void* d_out, int out_size, void* d_ws, size_t ws_size,
                              hipStream_t stream)
{
    const float* coeff = (const float*)d_in[0];
    const float* xin   = (const float*)d_in[1];
    float* out         = (float*)d_out;

    const int B = in_sizes[0] / TOTAL;   // 16384

    rnn_fused_kernel<<<B, HIDDEN, 0, stream>>>(coeff, xin, out);
}

// Round 10
// 160.721 us; speedup vs baseline: 1.4375x; 1.0298x over previous
//
#include <hip/hip_runtime.h>
#include <math.h>

#define HIDDEN 64
#define TOTAL  4417   // 5*64 + 1 + 64*64
#define TSTEPS 64

// coefficient layout per batch row:
//   w_ih  [0,   64)
//   w_hh  [64,  4160)   row-major [k][j]: 64 + k*64 + j
//   b_ih  [4160,4224)
//   b_hh  [4224,4288)
//   fc_w  [4288,4352)
//   fc_b  [4352,4353)
//   h0    [4353,4417)
//
// R9 post-mortem: hand-fused DPP loop (76 instr/step) landed at the SAME
// ~180us as R1's naive version. Invariant across all 1-wave variants:
// VALUBusy*dur ~= 140us ~= 64 MAC instrs/step at ~5cyc effective. The floor
// is MAC *instruction slots*. R10: v_pk_fma_f32 = 2 exact fp32 MACs per
// instruction -> 32 MAC instrs/step. h returns via 16 broadcast ds_read_b128
// (2 ping-pong halves through v88..v119).
//   v24..v87   W row (64, 32 even pairs)   v120..v123 acc (2 pk pairs)
//   v88..v119  h half (32, ping-pong)      v124 hn  v125 tmp  v126 x_t
//   v127 x cursor
// LDS: lds[0..63] = h, lds[64..127] = x row.

#define WL(r, o)   "global_load_dword v" #r ", %[wr], off offset:" #o "\n\t"
#define DR(rr, o)  "ds_read_b128 v[" #rr "], %[ha] offset:" #o "\n\t"
// acc[120:121] += h(even pair)*W(even pair); acc[122:123] += h(odd)*W(odd)
#define PK(h0_, h1_, w0_, w1_) \
    "v_pk_fma_f32 v[120:121], v[" #h0_ "], v[" #w0_ "], v[120:121]\n\t" \
    "v_pk_fma_f32 v[122:123], v[" #h1_ "], v[" #w1_ "], v[122:123]\n\t"

__global__
__attribute__((amdgpu_flat_work_group_size(64, 64)))
void rnn_fused_kernel(const float* __restrict__ coeff,
                      const float* __restrict__ xin,
                      float* __restrict__ out)
{
    const int b    = blockIdx.x;
    const int lane = threadIdx.x;              // 0..63, one wave per block

    const float* __restrict__ c = coeff + (size_t)b * TOTAL;

    __shared__ __align__(16) float lds[128];   // [0,64): h   [64,128): x row

    // ---- per-lane parameters ----
    const float wih  = c[lane];
    const float bias = c[4160 + lane] + c[4224 + lane];
    const float fcw  = c[4288 + lane];
    const float fcb  = c[4352];
    const float h0   = c[4353 + lane];
    const float xv   = xin[(size_t)b * TSTEPS + lane];  // lane t holds x[b][t]

    const float* wrow = c + HIDDEN + (size_t)lane * HIDDEN;

    // DS addresses: low 32 bits of a generic LDS pointer = DS byte offset.
    const unsigned ha = (unsigned)(unsigned long long)(const void*)lds;
    const unsigned hw = ha + 4u * (unsigned)lane;          // h write addr

    lds[lane]      = h0;   // ds_writes ordered before the asm ("memory")
    lds[64 + lane] = xv;

    float hn;
    asm volatile(
        // ---- W row into v24..v87 (once) ----
        WL(24,0)  WL(25,4)  WL(26,8)  WL(27,12)  WL(28,16)  WL(29,20)  WL(30,24)  WL(31,28)
        WL(32,32) WL(33,36) WL(34,40) WL(35,44)  WL(36,48)  WL(37,52)  WL(38,56)  WL(39,60)
        WL(40,64) WL(41,68) WL(42,72) WL(43,76)  WL(44,80)  WL(45,84)  WL(46,88)  WL(47,92)
        WL(48,96) WL(49,100) WL(50,104) WL(51,108) WL(52,112) WL(53,116) WL(54,120) WL(55,124)
        WL(56,128) WL(57,132) WL(58,136) WL(59,140) WL(60,144) WL(61,148) WL(62,152) WL(63,156)
        WL(64,160) WL(65,164) WL(66,168) WL(67,172) WL(68,176) WL(69,180) WL(70,184) WL(71,188)
        WL(72,192) WL(73,196) WL(74,200) WL(75,204) WL(76,208) WL(77,212) WL(78,216) WL(79,220)
        WL(80,224) WL(81,228) WL(82,232) WL(83,236) WL(84,240) WL(85,244) WL(86,248) WL(87,252)
        "s_mov_b32 s20, 0\n\t"
        "v_add_u32 v127, 0x100, %[ha]\n\t"     // x cursor = &lds[64]
        "s_waitcnt vmcnt(0)\n\t"               // W resident
        "s_waitcnt lgkmcnt(0)\n"               // h0/x ds_writes complete
        "9:\n\t"
        "ds_read_b32 v126, v127\n\t"           // x_t (uniform addr broadcast)
        DR(88:91, 0)   DR(92:95, 16)  DR(96:99, 32)   DR(100:103, 48)
        DR(104:107,64) DR(108:111,80) DR(112:115, 96) DR(116:119, 112)
        "v_add_u32 v127, 4, v127\n\t"
        "s_waitcnt lgkmcnt(0)\n\t"
        "v_fma_f32 v120, v126, %[wih], %[bias]\n\t"
        "v_mov_b32 v121, 0\n\t"
        "v_mov_b32 v122, 0\n\t"
        "v_mov_b32 v123, 0\n\t"
        // j = 0..31: 16 pk_fma (2 exact fp32 MACs each)
        PK(88:89,   90:91,   24:25, 26:27)
        PK(92:93,   94:95,   28:29, 30:31)
        PK(96:97,   98:99,   32:33, 34:35)
        PK(100:101, 102:103, 36:37, 38:39)
        PK(104:105, 106:107, 40:41, 42:43)
        PK(108:109, 110:111, 44:45, 46:47)
        PK(112:113, 114:115, 48:49, 50:51)
        PK(116:117, 118:119, 52:53, 54:55)
        // h[32..63] reads (reuse v88..v119; prior consumers already issued)
        DR(88:91, 128)  DR(92:95, 144)  DR(96:99, 160)  DR(100:103, 176)
        DR(104:107,192) DR(108:111,208) DR(112:115,224) DR(116:119, 240)
        "s_waitcnt lgkmcnt(0)\n\t"
        // j = 32..63
        PK(88:89,   90:91,   56:57, 58:59)
        PK(92:93,   94:95,   60:61, 62:63)
        PK(96:97,   98:99,   64:65, 66:67)
        PK(100:101, 102:103, 68:69, 70:71)
        PK(104:105, 106:107, 72:73, 74:75)
        PK(108:109, 110:111, 76:77, 78:79)
        PK(112:113, 114:115, 80:81, 82:83)
        PK(116:117, 118:119, 84:85, 86:87)
        // combine + tanh(a) = 1 - 2/(exp2(2a*log2e)+1)
        "v_pk_add_f32 v[120:121], v[120:121], v[122:123]\n\t"
        "v_add_f32 v120, v120, v121\n\t"
        "v_mul_f32 v125, 0x4038aa3b, v120\n\t" // a * 2*log2(e)
        "v_exp_f32 v125, v125\n\t"
        "s_nop 1\n\t"                          // trans-use safety
        "v_add_f32 v125, 1.0, v125\n\t"
        "v_rcp_f32 v125, v125\n\t"
        "s_nop 1\n\t"
        "v_fma_f32 v124, -2.0, v125, 1.0\n\t"  // hn
        "ds_write_b32 %[hw], v124\n\t"         // in-order DS: next read sees it
        "s_add_u32 s20, s20, 1\n\t"
        "s_cmp_lt_u32 s20, 64\n\t"
        "s_cbranch_scc1 9b\n\t"
        "s_waitcnt lgkmcnt(0)\n\t"
        "v_mov_b32 %[hn], v124\n\t"
        : [hn] "=v"(hn)
        : [wr] "v"(wrow), [ha] "v"(ha), [hw] "v"(hw),
          [wih] "v"(wih), [bias] "v"(bias)
        : "memory", "scc", "s20",
          "v24","v25","v26","v27","v28","v29","v30","v31",
          "v32","v33","v34","v35","v36","v37","v38","v39",
          "v40","v41","v42","v43","v44","v45","v46","v47",
          "v48","v49","v50","v51","v52","v53","v54","v55",
          "v56","v57","v58","v59","v60","v61","v62","v63",
          "v64","v65","v66","v67","v68","v69","v70","v71",
          "v72","v73","v74","v75","v76","v77","v78","v79",
          "v80","v81","v82","v83","v84","v85","v86","v87",
          "v88","v89","v90","v91","v92","v93","v94","v95",
          "v96","v97","v98","v99","v100","v101","v102","v103",
          "v104","v105","v106","v107","v108","v109","v110","v111",
          "v112","v113","v114","v115","v116","v117","v118","v119",
          "v120","v121","v122","v123","v124","v125","v126","v127");

    // ---- readout: pred = sum_k h[k]*fc_w[k] + fc_b ----
    float p = hn * fcw;
    #pragma unroll
    for (int off = 32; off > 0; off >>= 1)
        p += __shfl_xor(p, off, 64);

    if (lane == 0) out[b] = p + fcb;
}

extern "C" void kernel_launch(void* const* d_in, const int* in_sizes, int n_in,
                              void* d_out, int out_size, void* d_ws, size_t ws_size,
                              hipStream_t stream)
{
    const float* coeff = (const float*)d_in[0];
    const float* xin   = (const float*)d_in[1];
    float* out         = (float*)d_out;

    const int B = in_sizes[0] / TOTAL;   // 16384

    rnn_fused_kernel<<<B, HIDDEN, 0, stream>>>(coeff, xin, out);
}